// Round 2
// baseline (210.018 us; speedup 1.0000x reference)
//
#include <hip/hip_runtime.h>
#include <stdint.h>

typedef __bf16 bf16x8 __attribute__((ext_vector_type(8)));
typedef float floatx4 __attribute__((ext_vector_type(4)));
typedef float floatx4u __attribute__((ext_vector_type(4), aligned(4)));
typedef unsigned int u32x4 __attribute__((ext_vector_type(4)));
typedef unsigned short u16;
typedef unsigned short u16x8 __attribute__((ext_vector_type(8)));
typedef unsigned int u32;

#define CIN   64
#define COUT  128
#define H_    1855
#define KNB   6
#define KTOT  448      // (1+KNB)*CIN
#define NSTEPS 14      // KTOT / 32

// LDS geometry (bytes): piece (hl,s) = 256 B; hl row = 8 s-slots = 2048 B,
// padded +16 -> 2064. Buffer = 16 hl rows. Per-wave region = 2 rows = 4128 B
// (wave w stages rows 2w,2w+1 AND overlays its epilogue C-stage there).
#define HLROW 2064
#define WROW  4128
#define BUFSZ 33024

// ws layout (bytes)
#define WP_OFF     ((size_t)H_ * 4096 * 2)                 // xt3: bf16 [h][4096]
#define CINV_OFF   (WP_OFF + (size_t)COUT * KTOT * 2)
#define ZERO_OFF   (CINV_OFF + 7424)                       // 256-B aligned zero page
#define SRCOFF_OFF (ZERO_OFF + 1024)                       // u32 [H][8] gather row offsets
#define INVOFF 0xFFFFFFFFu

#define PIN4(v) asm volatile("" : "+v"(v))

typedef __attribute__((address_space(1))) unsigned int as1_u32;
typedef __attribute__((address_space(3))) unsigned int as3_u32;
static __device__ __forceinline__ void ld16_to_lds(const void* g, void* l) {
    __builtin_amdgcn_global_load_lds((const as1_u32*)g, (as3_u32*)l, 16, 0, 0);
}

static __device__ inline u16 f32_to_bf16(float f) {
    u32 u = __float_as_uint(f);
    u32 r = (u + 0x7FFFu + ((u >> 16) & 1u)) >> 16;
    return (u16)r;
}

// ---- K1 (fused): transpose x f32 [bc][h] -> xt3 bf16 [h][bc], plus
// weight-pack / inverse-counts / zero-page / gather-offset table in the
// blockIdx.y==64 stripe. One launch instead of two.
__global__ __launch_bounds__(256) void k_prep(const float* __restrict__ x,
                                              const float* __restrict__ wc,
                                              const float* __restrict__ wn,
                                              const int* __restrict__ nbr,
                                              u16* __restrict__ xt3,
                                              u16* __restrict__ wp,
                                              float* __restrict__ cInvG,
                                              u32* __restrict__ zeroPg,
                                              u32* __restrict__ srcOff) {
    int tid = threadIdx.x;
    if (blockIdx.y == 64) {            // ---- pack stripe (29 blocks, strided)
        for (int tg = blockIdx.x * 256 + tid; tg < COUT * KTOT; tg += 29 * 256) {
            if (tg < 64) zeroPg[tg] = 0u;
            if (tg < H_) {
                int cnt = 1;
#pragma unroll
                for (int j = 0; j < KNB; ++j) cnt += (nbr[tg * KNB + j] >= 0) ? 1 : 0;
                cInvG[tg] = 1.0f / (float)cnt;
            }
            if (tg < H_ * 8) {
                int h = tg >> 3, s = tg & 7;
                u32 e;
                if (s == 0) e = (u32)h * 8192u;
                else if (s <= 6) {
                    int n = nbr[h * KNB + (s - 1)];
                    e = (n >= 0) ? (u32)n * 8192u : INVOFF;
                } else e = INVOFF;
                srcOff[tg] = e;
            }
            int o = tg / KTOT;
            int rem = tg - o * KTOT;
            int s = rem >> 6, c = rem & 63;
            float v = (s == 0) ? wc[o * CIN + c]
                               : wn[(o * CIN + c) * KNB + (s - 1)];
            wp[tg] = f32_to_bf16(v);
        }
        return;
    }
    // ---- transpose stripe
    __shared__ u16 tile[64][65];
    int h0  = blockIdx.x * 64;
    int bc0 = blockIdx.y * 64;
    int lh   = tid & 15;               // h-quad (4 h per thread)
    int rowi = tid >> 4;               // 0..15
    bool safe = (h0 + 64 <= H_);       // float4 read fully in-bounds
#pragma unroll
    for (int i = 0; i < 4; ++i) {
        int row = i * 16 + rowi;
        int h = h0 + lh * 4;
        u16 v4[4];
        if (safe) {
            floatx4u f = *(const floatx4u*)(x + (size_t)(bc0 + row) * H_ + h);
#pragma unroll
            for (int j = 0; j < 4; ++j) v4[j] = f32_to_bf16(f[j]);
        } else {
#pragma unroll
            for (int j = 0; j < 4; ++j) {
                int hh = h + j;
                v4[j] = (hh < H_) ? f32_to_bf16(x[(size_t)(bc0 + row) * H_ + hh]) : (u16)0;
            }
        }
#pragma unroll
        for (int j = 0; j < 4; ++j) tile[row][lh * 4 + j] = v4[j];
    }
    __syncthreads();
    // each thread packs 8 bc (u16x8) for one h -> one 16-B store.
    int bg = tid & 7;
    int hb = tid >> 3;
#pragma unroll
    for (int ii = 0; ii < 2; ++ii) {
        int hl = ii * 32 + hb;
        int hh = h0 + hl;
        u16x8 v;
#pragma unroll
        for (int j = 0; j < 8; ++j) v[j] = tile[bg * 8 + j][hl];
        if (hh < H_)
            *(u16x8*)(xt3 + (size_t)hh * 4096 + bc0 + bg * 8) = v;
    }
}

// ---- K3: main gather-GEMM ------------------------------------------------
// grid = 928 = 29 h-supertiles x 32 b-pairs (XCD = blk&7). Block: 512 thr =
// 8 waves, each wave owns M=16 output rows (afrag = 14 u32x4 = 56 VGPR).
// 2 blocks/CU (LDS 66 KB) -> 16 waves/CU = 50% occupancy ceiling (was 8).
// Counted-vmcnt schedule: mid-loop wait = vmcnt(20) retiring only the 4 t2
// gathers; the 16 pair-0 stores stay in flight ~2 phases before any drain.
__global__ __launch_bounds__(512, 4) void k_main(const u16* __restrict__ xt3,
                                                 const u16* __restrict__ wp,
                                                 const float* __restrict__ bias,
                                                 const float* __restrict__ cInvG,
                                                 const u32* __restrict__ srcOff,
                                                 float* __restrict__ out) {
    __shared__ __align__(16) char LDS[2 * BUFSZ];

    int tid  = threadIdx.x;
    int gbl  = blockIdx.x;
    int bp   = gbl & 31;          // b-pair; XCD = gbl&7
    int hs   = gbl >> 5;          // 0..28
    int b0   = bp * 2;
    int h0   = hs * 64;

    int lane = tid & 63;
    int wave = tid >> 6;          // 0..7
    int col  = lane & 15;
    int quad = lane >> 4;
    int m0w  = wave * 16;
    int lane16 = lane & 15;
    int ssub = lane >> 4;
    int bl   = lane16 >> 3;
    int chunk = lane16 & 7;

    const char* xb = (const char*)xt3;   // == d_ws base; all offsets relative

    // A fragments: wave's 16 rows, A[m=col][k=quad*8+j]. 56 VGPR, pinned.
    u32x4 afrag[NSTEPS];
    {
        int o = m0w + col;
#pragma unroll
        for (int kk = 0; kk < NSTEPS; ++kk)
            afrag[kk] = *(const u32x4*)(wp + o * KTOT + kk * 32 + quad * 8);
    }
#pragma unroll
    for (int kk = 0; kk < NSTEPS; ++kk) PIN4(afrag[kk]);

    float biasv[4];
#pragma unroll
    for (int r = 0; r < 4; ++r) biasv[r] = bias[m0w + quad * 4 + r];

    float icv[4];
#pragma unroll
    for (int t = 0; t < 4; ++t) {
        int hic = h0 + t * 16 + col;
        icv[t] = cInvG[hic < H_ ? hic : 0];
    }

    // Per-lane staging byte-offsets: wave stages hl rows {2w, 2w+1}, 4
    // global_load_lds per tile (i: hl=i&1, s-group=i>>1; lanes: 4 s x 16 chunks).
    u32 colOff = (u32)((b0 + bl) * 128 + chunk * 16);
    u32 zOff   = (u32)ZERO_OFF + (u32)(lane16 * 16);
    u32 offs[4][4];
#pragma unroll
    for (int t = 0; t < 4; ++t)
#pragma unroll
        for (int i = 0; i < 4; ++i) {
            int hh = h0 + t * 16 + wave * 2 + (i & 1);
            int s  = (i >> 1) * 4 + ssub;
            u32 e = (hh < H_) ? srcOff[hh * 8 + s] : INVOFF;
            offs[t][i] = (e == INVOFF) ? zOff : (e + colOff);
        }

    int rb0 = col * HLROW + quad * 16;
    int rb1 = rb0 + 128;
    char* buf0 = LDS;
    char* buf1 = LDS + BUFSZ;

#define STAGE(t, bufp) do {                                                   \
    char* _d = (bufp) + wave * WROW;                                          \
    _Pragma("unroll")                                                         \
    for (int _i = 0; _i < 4; ++_i)                                            \
        ld16_to_lds(xb + offs[t][_i], _d + (_i & 1) * HLROW + (_i >> 1) * 1024); \
} while (0)

#define COMPUTE(accv, bufp) do {                                              \
    accv[0] = (floatx4){0.0f, 0.0f, 0.0f, 0.0f};                              \
    accv[1] = (floatx4){0.0f, 0.0f, 0.0f, 0.0f};                              \
    __builtin_amdgcn_s_setprio(1);                                            \
    _Pragma("unroll")                                                         \
    for (int kk = 0; kk < NSTEPS; ++kk) {                                     \
        int koff = (kk >> 1) * 256 + (kk & 1) * 64;                           \
        bf16x8 bfa = *(const bf16x8*)((bufp) + rb0 + koff);                   \
        bf16x8 bfb = *(const bf16x8*)((bufp) + rb1 + koff);                   \
        bf16x8 a = __builtin_bit_cast(bf16x8, afrag[kk]);                     \
        accv[0] = __builtin_amdgcn_mfma_f32_16x16x32_bf16(a, bfa, accv[0], 0, 0, 0); \
        accv[1] = __builtin_amdgcn_mfma_f32_16x16x32_bf16(a, bfb, accv[1], 0, 0, 0); \
    }                                                                         \
    __builtin_amdgcn_s_setprio(0);                                            \
} while (0)

// E write into wave-private skewed region (coincides with own staging rows):
// idx XOR (quad<<3): quads {0,1}->banks 0..15, {2,3}->16..31 => 2-way, free.
#define EPIW(Ew, pp, t, accv) do {                                            \
    float _ic = icv[(pp) * 2 + (t)];                                          \
    _Pragma("unroll") for (int _n = 0; _n < 2; ++_n)                          \
    _Pragma("unroll") for (int _r = 0; _r < 4; ++_r) {                        \
        int _idx = ((_n) * 32 + (t) * 16 + col) ^ (quad << 3);                \
        (Ew)[(quad * 4 + _r) * 64 + _idx] = accv[_n][_r] * _ic + biasv[_r];   \
    }                                                                         \
} while (0)

// readback + store: lane=(g=b, h5=32 consecutive h) -> 128-B segments.
#define EPIS(Ew, pp) do {                                                     \
    int _h5 = lane & 31, _g = lane >> 5;                                      \
    int _hh = h0 + (pp) * 32 + _h5;                                           \
    bool _hv = _hh < H_;                                                      \
    size_t _ob = (size_t)(b0 + _g) * ((size_t)COUT * H_)                      \
               + (size_t)m0w * H_ + _hh;                                      \
    _Pragma("unroll")                                                         \
    for (int _j = 0; _j < 16; ++_j) {                                         \
        float _v = (Ew)[_j * 64 + ((_g * 32 + _h5) ^ (((_j >> 2) & 3) << 3))]; \
        if (_hv) out[_ob + (size_t)_j * H_] = _v;                             \
    }                                                                         \
} while (0)

#define ABAR0()  do { asm volatile("s_waitcnt vmcnt(0) lgkmcnt(0)" ::: "memory");  __builtin_amdgcn_s_barrier(); } while (0)
#define ABAR20() do { asm volatile("s_waitcnt vmcnt(20) lgkmcnt(0)" ::: "memory"); __builtin_amdgcn_s_barrier(); } while (0)
#define BBAR()   do { asm volatile("s_waitcnt lgkmcnt(0)" ::: "memory");           __builtin_amdgcn_s_barrier(); } while (0)
#define LGW()    asm volatile("s_waitcnt lgkmcnt(0)" ::: "memory")

    floatx4 accA[2], accB[2];

    STAGE(0, buf0);               // FIFO: 4L
    ABAR0();                      // t0 visible (drains prologue too)
    STAGE(1, buf1);               // [4L]
    COMPUTE(accA, buf0);          // t0
    ABAR0();                      // t1 visible (loads aged one compute phase)
    STAGE(2, buf0);               // [4L]
    COMPUTE(accB, buf1);          // t1
    BBAR();                       // buf1 reads done block-wide; NO vm drain
    {
        float* E1 = (float*)(buf1 + wave * WROW);   // wave-private overlay
        EPIW(E1, 0, 0, accA);
        EPIW(E1, 0, 1, accB);
        EPIS(E1, 0);              // 16 stores; FIFO: [4L t2][16S]
        LGW();                    // own E reads complete (no barrier)
        STAGE(3, buf1);           // own region only -> safe; FIFO: [4L][16S][4L]
    }
    ABAR20();                     // retires exactly the 4 t2 loads; stores fly on
    COMPUTE(accA, buf0);          // t2
    ABAR0();                      // t3 visible (stores now ~2 phases old, cheap)
    COMPUTE(accB, buf1);          // t3
    BBAR();
    {
        float* E0 = (float*)(buf0 + wave * WROW);
        EPIW(E0, 1, 0, accA);
        EPIW(E0, 1, 1, accB);
        EPIS(E0, 1);              // final stores drain at endpgm
    }

#undef STAGE
#undef COMPUTE
#undef EPIW
#undef EPIS
#undef ABAR0
#undef ABAR20
#undef BBAR
#undef LGW
}

extern "C" void kernel_launch(void* const* d_in, const int* in_sizes, int n_in,
                              void* d_out, int out_size, void* d_ws, size_t ws_size,
                              hipStream_t stream) {
    const float* x    = (const float*)d_in[0];   // f32 [64,64,1855]
    const int*   nbr  = (const int*)d_in[1];     // int32 [1855,6]
    const float* wc   = (const float*)d_in[2];   // f32 [128,64]
    const float* wn   = (const float*)d_in[3];   // f32 [128,64,6]
    const float* bias = (const float*)d_in[4];   // f32 [128]

    u16*   xt3    = (u16*)d_ws;
    u16*   wp     = (u16*)((char*)d_ws + WP_OFF);
    float* cInvG  = (float*)((char*)d_ws + CINV_OFF);
    u32*   zeroPg = (u32*)((char*)d_ws + ZERO_OFF);
    u32*   srcOff = (u32*)((char*)d_ws + SRCOFF_OFF);

    k_prep<<<dim3(29, 65), dim3(256), 0, stream>>>(
        x, wc, wn, nbr, xt3, wp, cInvG, zeroPg, srcOff);
    k_main<<<dim3(928), dim3(512), 0, stream>>>(
        xt3, wp, bias, cInvG, srcOff, (float*)d_out);
}

// Round 3
// 130.497 us; speedup vs baseline: 1.6094x; 1.6094x over previous
//
#include <hip/hip_runtime.h>
#include <stdint.h>

typedef __bf16 bf16x8 __attribute__((ext_vector_type(8)));
typedef float floatx4 __attribute__((ext_vector_type(4)));
typedef float floatx4u __attribute__((ext_vector_type(4), aligned(4)));
typedef unsigned int u32x4 __attribute__((ext_vector_type(4)));
typedef unsigned short u16;
typedef unsigned short u16x8 __attribute__((ext_vector_type(8)));
typedef unsigned int u32;

#define CIN   64
#define COUT  128
#define H_    1855
#define KNB   6
#define KTOT  448      // (1+KNB)*CIN
#define NSTEPS 14      // KTOT / 32

// Half-buffer geometry: half-tile = 16 hl rows x 4 s-slots. Row = 4*256+16
// pad = 1040 B (pad keeps b128 reads at 2-way banks: 1040/4 mod 32 == 4).
// 4 half-buffers rotate (k&3); k = half index 0..7, tile = k>>1, sg = k&1.
#define HROW   1040
#define HBUFSZ 16640   // 16 * HROW

// ws layout (bytes)
#define WP_OFF     ((size_t)H_ * 4096 * 2)                 // xt3: bf16 [h][4096]
#define CINV_OFF   (WP_OFF + (size_t)COUT * KTOT * 2)
#define ZERO_OFF   (CINV_OFF + 7424)                       // 256-B aligned zero page
#define SRCOFF_OFF (ZERO_OFF + 1024)                       // u32 [H][8] gather row offsets
#define INVOFF 0xFFFFFFFFu

#define PIN4(v) asm volatile("" : "+v"(v))

typedef __attribute__((address_space(1))) unsigned int as1_u32;
typedef __attribute__((address_space(3))) unsigned int as3_u32;
static __device__ __forceinline__ void ld16_to_lds(const void* g, void* l) {
    __builtin_amdgcn_global_load_lds((const as1_u32*)g, (as3_u32*)l, 16, 0, 0);
}

static __device__ inline u16 f32_to_bf16(float f) {
    u32 u = __float_as_uint(f);
    u32 r = (u + 0x7FFFu + ((u >> 16) & 1u)) >> 16;
    return (u16)r;
}

// ---- K1 (fused): transpose x f32 [bc][h] -> xt3 bf16 [h][bc], plus
// weight-pack / inverse-counts / zero-page / gather-offset table in the
// blockIdx.y==64 stripe. (Verified in round 2.)
__global__ __launch_bounds__(256) void k_prep(const float* __restrict__ x,
                                              const float* __restrict__ wc,
                                              const float* __restrict__ wn,
                                              const int* __restrict__ nbr,
                                              u16* __restrict__ xt3,
                                              u16* __restrict__ wp,
                                              float* __restrict__ cInvG,
                                              u32* __restrict__ zeroPg,
                                              u32* __restrict__ srcOff) {
    int tid = threadIdx.x;
    if (blockIdx.y == 64) {            // ---- pack stripe (29 blocks, strided)
        for (int tg = blockIdx.x * 256 + tid; tg < COUT * KTOT; tg += 29 * 256) {
            if (tg < 64) zeroPg[tg] = 0u;
            if (tg < H_) {
                int cnt = 1;
#pragma unroll
                for (int j = 0; j < KNB; ++j) cnt += (nbr[tg * KNB + j] >= 0) ? 1 : 0;
                cInvG[tg] = 1.0f / (float)cnt;
            }
            if (tg < H_ * 8) {
                int h = tg >> 3, s = tg & 7;
                u32 e;
                if (s == 0) e = (u32)h * 8192u;
                else if (s <= 6) {
                    int n = nbr[h * KNB + (s - 1)];
                    e = (n >= 0) ? (u32)n * 8192u : INVOFF;
                } else e = INVOFF;
                srcOff[tg] = e;
            }
            int o = tg / KTOT;
            int rem = tg - o * KTOT;
            int s = rem >> 6, c = rem & 63;
            float v = (s == 0) ? wc[o * CIN + c]
                               : wn[(o * CIN + c) * KNB + (s - 1)];
            wp[tg] = f32_to_bf16(v);
        }
        return;
    }
    // ---- transpose stripe
    __shared__ u16 tile[64][65];
    int h0  = blockIdx.x * 64;
    int bc0 = blockIdx.y * 64;
    int lh   = tid & 15;               // h-quad (4 h per thread)
    int rowi = tid >> 4;               // 0..15
    bool safe = (h0 + 64 <= H_);       // float4 read fully in-bounds
#pragma unroll
    for (int i = 0; i < 4; ++i) {
        int row = i * 16 + rowi;
        int h = h0 + lh * 4;
        u16 v4[4];
        if (safe) {
            floatx4u f = *(const floatx4u*)(x + (size_t)(bc0 + row) * H_ + h);
#pragma unroll
            for (int j = 0; j < 4; ++j) v4[j] = f32_to_bf16(f[j]);
        } else {
#pragma unroll
            for (int j = 0; j < 4; ++j) {
                int hh = h + j;
                v4[j] = (hh < H_) ? f32_to_bf16(x[(size_t)(bc0 + row) * H_ + hh]) : (u16)0;
            }
        }
#pragma unroll
        for (int j = 0; j < 4; ++j) tile[row][lh * 4 + j] = v4[j];
    }
    __syncthreads();
    int bg = tid & 7;
    int hb = tid >> 3;
#pragma unroll
    for (int ii = 0; ii < 2; ++ii) {
        int hl = ii * 32 + hb;
        int hh = h0 + hl;
        u16x8 v;
#pragma unroll
        for (int j = 0; j < 8; ++j) v[j] = tile[bg * 8 + j][hl];
        if (hh < H_)
            *(u16x8*)(xt3 + (size_t)hh * 4096 + bc0 + bg * 8) = v;
    }
}

// ---- K3: main gather-GEMM, 8-phase half-tile pipeline ---------------------
// grid = 928 = 29 h-supertiles x 32 b-pairs (XCD = blk&7). Block: 256 thr =
// 4 waves, M=32/wave (afrag 112 regs -> AGPR), 2 blocks/CU, 66.5 KB LDS.
// K=448 split into halves at the s-group seam (slots 0-3 = kk 0..7, slots
// 4-6 = kk 8..13). 4 rotating half-buffers; stage issued 3 half-phases before
// consumption; counted-vmcnt ladder never drains young stores.
__global__ __launch_bounds__(256, 2) void k_main(const u16* __restrict__ xt3,
                                                 const u16* __restrict__ wp,
                                                 const float* __restrict__ bias,
                                                 const float* __restrict__ cInvG,
                                                 const u32* __restrict__ srcOff,
                                                 float* __restrict__ out) {
    __shared__ __align__(16) char LDS[4 * HBUFSZ];

    int tid  = threadIdx.x;
    int gbl  = blockIdx.x;
    int bp   = gbl & 31;          // b-pair; XCD = gbl&7
    int hs   = gbl >> 5;          // 0..28
    int b0   = bp * 2;
    int h0   = hs * 64;

    int lane = tid & 63;
    int wave = tid >> 6;          // 0..3
    int col  = lane & 15;
    int quad = lane >> 4;
    int m0w  = wave * 32;
    int lane16 = lane & 15;
    int ssub = lane >> 4;
    int bl   = lane16 >> 3;
    int chunk = lane16 & 7;

    const char* xb = (const char*)xt3;   // == d_ws base; all offsets relative

    // A fragments (weights): A[m=col][k=quad*8+j]; 112 regs -> AGPRs.
    u32x4 afrag[2][NSTEPS];
#pragma unroll
    for (int mt = 0; mt < 2; ++mt) {
        int o = m0w + mt * 16 + col;
#pragma unroll
        for (int kk = 0; kk < NSTEPS; ++kk)
            afrag[mt][kk] = *(const u32x4*)(wp + o * KTOT + kk * 32 + quad * 8);
    }
#pragma unroll
    for (int mt = 0; mt < 2; ++mt)
#pragma unroll
        for (int kk = 0; kk < NSTEPS; ++kk)
            PIN4(afrag[mt][kk]);

    float biasv[2][4];
#pragma unroll
    for (int mt = 0; mt < 2; ++mt)
#pragma unroll
        for (int r = 0; r < 4; ++r)
            biasv[mt][r] = bias[m0w + mt * 16 + quad * 4 + r];

    float icv[4];
#pragma unroll
    for (int t = 0; t < 4; ++t) {
        int hic = h0 + t * 16 + col;
        icv[t] = cInvG[hic < H_ ? hic : 0];
    }

    // Per-lane staging byte-offsets: offs[tile][sg][i]; wave stages hl rows
    // wave*4+i; per instruction 64 lanes = 4 s-pieces (ssub) x 16 chunks.
    u32 colOff = (u32)((b0 + bl) * 128 + chunk * 16);
    u32 zOff   = (u32)ZERO_OFF + (u32)(lane16 * 16);
    u32 offs[4][2][4];
#pragma unroll
    for (int t = 0; t < 4; ++t)
#pragma unroll
        for (int sg = 0; sg < 2; ++sg)
#pragma unroll
            for (int i = 0; i < 4; ++i) {
                int hh = h0 + t * 16 + wave * 4 + i;
                int s  = sg * 4 + ssub;
                u32 e = (hh < H_) ? srcOff[hh * 8 + s] : INVOFF;
                offs[t][sg][i] = (e == INVOFF) ? zOff : (e + colOff);
            }

    int rb0 = col * HROW + quad * 16;
    int rb1 = rb0 + 128;
    char* bufA0 = LDS;                 // half-buffer k&3 == 0
    char* bufA1 = LDS + HBUFSZ;        // 1
    char* bufA2 = LDS + 2 * HBUFSZ;    // 2
    char* bufA3 = LDS + 3 * HBUFSZ;    // 3
    bool bnd = (hs == 28);

#define SGH(t, sg, bufp) do {                                                 \
    char* _d = (bufp) + (wave * 4) * HROW;                                    \
    _Pragma("unroll")                                                         \
    for (int _i = 0; _i < 4; ++_i)                                            \
        ld16_to_lds(xb + offs[t][sg][_i], _d + _i * HROW);                    \
} while (0)

#define CA(accv, bufp) do {  /* k-steps 0..7, zero-init */                    \
    _Pragma("unroll") for (int _m = 0; _m < 2; ++_m)                          \
    _Pragma("unroll") for (int _n = 0; _n < 2; ++_n)                          \
        accv[_m][_n] = (floatx4){0.0f, 0.0f, 0.0f, 0.0f};                     \
    __builtin_amdgcn_s_setprio(1);                                            \
    _Pragma("unroll")                                                         \
    for (int kk = 0; kk < 8; ++kk) {                                          \
        int koff = (kk >> 1) * 256 + (kk & 1) * 64;                           \
        bf16x8 bfa = *(const bf16x8*)((bufp) + rb0 + koff);                   \
        bf16x8 bfb = *(const bf16x8*)((bufp) + rb1 + koff);                   \
        bf16x8 a0 = __builtin_bit_cast(bf16x8, afrag[0][kk]);                 \
        bf16x8 a1 = __builtin_bit_cast(bf16x8, afrag[1][kk]);                 \
        accv[0][0] = __builtin_amdgcn_mfma_f32_16x16x32_bf16(a0, bfa, accv[0][0], 0, 0, 0); \
        accv[1][0] = __builtin_amdgcn_mfma_f32_16x16x32_bf16(a1, bfa, accv[1][0], 0, 0, 0); \
        accv[0][1] = __builtin_amdgcn_mfma_f32_16x16x32_bf16(a0, bfb, accv[0][1], 0, 0, 0); \
        accv[1][1] = __builtin_amdgcn_mfma_f32_16x16x32_bf16(a1, bfb, accv[1][1], 0, 0, 0); \
    }                                                                         \
    __builtin_amdgcn_s_setprio(0);                                            \
} while (0)

#define CB(accv, bufp) do {  /* k-steps 8..13, accumulate */                  \
    __builtin_amdgcn_s_setprio(1);                                            \
    _Pragma("unroll")                                                         \
    for (int kk = 8; kk < 14; ++kk) {                                         \
        int koff = ((kk - 8) >> 1) * 256 + (kk & 1) * 64;                     \
        bf16x8 bfa = *(const bf16x8*)((bufp) + rb0 + koff);                   \
        bf16x8 bfb = *(const bf16x8*)((bufp) + rb1 + koff);                   \
        bf16x8 a0 = __builtin_bit_cast(bf16x8, afrag[0][kk]);                 \
        bf16x8 a1 = __builtin_bit_cast(bf16x8, afrag[1][kk]);                 \
        accv[0][0] = __builtin_amdgcn_mfma_f32_16x16x32_bf16(a0, bfa, accv[0][0], 0, 0, 0); \
        accv[1][0] = __builtin_amdgcn_mfma_f32_16x16x32_bf16(a1, bfa, accv[1][0], 0, 0, 0); \
        accv[0][1] = __builtin_amdgcn_mfma_f32_16x16x32_bf16(a0, bfb, accv[0][1], 0, 0, 0); \
        accv[1][1] = __builtin_amdgcn_mfma_f32_16x16x32_bf16(a1, bfb, accv[1][1], 0, 0, 0); \
    }                                                                         \
    __builtin_amdgcn_s_setprio(0);                                            \
} while (0)

// Pair epilogue: E overlays the wave's own 4 rows of a FREED half-buffer
// (4 KB used of 4160). Layout: E[o_local(0..31)][32 floats], 4-float groups
// XOR-swizzled by (o&7) -> conflict-free b128 readback, 2-way writes.
// Per b-substep: write 16 f32, read 4x b128, store 4x float4 (128-B segs).
// Store count = 8/wave (exact, for the vmcnt ladder); BND (last epilogue
// only, uncounted) masks the single ragged float at h=1855.
#define EPI(pp, a0v, a1v, Ebuf, BND) do {                                     \
    float* _E = (float*)((Ebuf) + (wave * 4) * HROW);                         \
    int _o8 = lane >> 3, _h4 = lane & 7;                                      \
    _Pragma("unroll")                                                         \
    for (int _nt = 0; _nt < 2; ++_nt) {                                       \
        asm volatile("s_waitcnt lgkmcnt(0)" ::: "memory");                    \
        _Pragma("unroll") for (int _mt = 0; _mt < 2; ++_mt)                   \
        _Pragma("unroll") for (int _r = 0; _r < 4; ++_r) {                    \
            int _ol = _mt * 16 + quad * 4 + _r;                               \
            int _x0 = ((col >> 2) ^ (_ol & 7));                               \
            int _x1 = (((16 + col) >> 2) ^ (_ol & 7));                        \
            _E[_ol * 32 + (_x0 << 2) + (col & 3)] =                           \
                a0v[_mt][_nt][_r] * icv[(pp) * 2]     + biasv[_mt][_r];       \
            _E[_ol * 32 + (_x1 << 2) + (col & 3)] =                           \
                a1v[_mt][_nt][_r] * icv[(pp) * 2 + 1] + biasv[_mt][_r];       \
        }                                                                     \
        asm volatile("s_waitcnt lgkmcnt(0)" ::: "memory");                    \
        _Pragma("unroll")                                                     \
        for (int _q = 0; _q < 4; ++_q) {                                      \
            int _ol = _q * 8 + _o8;                                           \
            floatx4 _v = *(const floatx4*)(_E + _ol * 32 + ((_h4 ^ (_ol & 7)) << 2)); \
            int _hh = h0 + (pp) * 32 + _h4 * 4;                               \
            float* _dst = out + (size_t)(b0 + _nt) * ((size_t)COUT * H_)      \
                        + (size_t)(m0w + _ol) * H_ + _hh;                     \
            if (!(BND)) {                                                     \
                *(floatx4u*)_dst = _v;                                        \
            } else {                                                          \
                _Pragma("unroll") for (int _e = 0; _e < 4; ++_e)              \
                    if (_hh + _e < H_) _dst[_e] = _v[_e];                     \
            }                                                                 \
        }                                                                     \
    }                                                                         \
} while (0)

#define VW(n)  asm volatile("s_waitcnt vmcnt(" #n ") lgkmcnt(0)" ::: "memory")
#define BAR()  __builtin_amdgcn_s_barrier()

    floatx4 acc0[2][2], acc1[2][2];

    // Prologue: 3 half-stages in flight (12 loads/wave).
    SGH(0, 0, bufA0);                 // S0
    SGH(0, 1, bufA1);                 // S1
    SGH(1, 0, bufA2);                 // S2  -> vm FIFO [S0 S1 S2]

    VW(8);  BAR(); SGH(1, 1, bufA3);  CA(acc0, bufA0);   // ph0: C0 (t0 A)
    VW(8);  BAR(); SGH(2, 0, bufA0);  CB(acc0, bufA1);   // ph1: C1 (t0 B)
    VW(8);  BAR(); SGH(2, 1, bufA1);  CA(acc1, bufA2);   // ph2: C2 (t1 A)
    VW(8);  BAR();                    CB(acc1, bufA3);   // ph3: C3 (t1 B)
    EPI(0, acc0, acc1, bufA2, false);                    //  pair0 -> +8 stores
    VW(12); BAR(); SGH(3, 0, bufA2);  CA(acc0, bufA0);   // ph4: C4 (t2 A)
    VW(12); BAR(); SGH(3, 1, bufA3);  CB(acc0, bufA1);   // ph5: C5 (t2 B)
    VW(4);  BAR();                    CA(acc1, bufA2);   // ph6: C6 (t3 A)
    VW(0);  BAR();                    CB(acc1, bufA3);   // ph7: C7 (t3 B)
    EPI(1, acc0, acc1, bufA2, bnd);                      //  pair1; drains at end

#undef SGH
#undef CA
#undef CB
#undef EPI
#undef VW
#undef BAR
}

extern "C" void kernel_launch(void* const* d_in, const int* in_sizes, int n_in,
                              void* d_out, int out_size, void* d_ws, size_t ws_size,
                              hipStream_t stream) {
    const float* x    = (const float*)d_in[0];   // f32 [64,64,1855]
    const int*   nbr  = (const int*)d_in[1];     // int32 [1855,6]
    const float* wc   = (const float*)d_in[2];   // f32 [128,64]
    const float* wn   = (const float*)d_in[3];   // f32 [128,64,6]
    const float* bias = (const float*)d_in[4];   // f32 [128]

    u16*   xt3    = (u16*)d_ws;
    u16*   wp     = (u16*)((char*)d_ws + WP_OFF);
    float* cInvG  = (float*)((char*)d_ws + CINV_OFF);
    u32*   zeroPg = (u32*)((char*)d_ws + ZERO_OFF);
    u32*   srcOff = (u32*)((char*)d_ws + SRCOFF_OFF);

    k_prep<<<dim3(29, 65), dim3(256), 0, stream>>>(
        x, wc, wn, nbr, xt3, wp, cInvG, zeroPg, srcOff);
    k_main<<<dim3(928), dim3(256), 0, stream>>>(
        xt3, wp, bias, cInvG, srcOff, (float*)d_out);
}